// Round 9
// baseline (200.827 us; speedup 1.0000x reference)
//
#include <hip/hip_runtime.h>
#include <hip/hip_bf16.h>

#define DF 128
#define BSH 6                 // bucket = dst >> 6  (64 nodes / bucket)
#define BNODES 64
#define NBMAX 1024            // max buckets (50000/64 = 782)
#define CHUNK 8192            // edges per hist/bin block
#define TILE 2048             // edges per aggregation LDS tile (bucket ~1024)
#define ASTRIDE 68            // uints per abuf row (64 data + 4 pad)
#define SRCMASK 0x03ffffffu   // src in low 26 bits, dstLocal in bits 26..31

typedef __attribute__((ext_vector_type(8))) short short8;
typedef __attribute__((ext_vector_type(4))) float floatx4;

__device__ __forceinline__ ushort f2bf(float f) {
    __hip_bfloat16 h = __float2bfloat16(f);   // RNE
    return *reinterpret_cast<ushort*>(&h);
}

// ---------------------------------------------------------------------------
// Fused prep: [0,B_) hist blocks | [B_,B_+64) weight convert | rest x convert.
// ---------------------------------------------------------------------------
__global__ __launch_bounds__(256) void prep_kernel(
    const float* __restrict__ x, ushort* __restrict__ xbf, int n4,
    const float* __restrict__ W1, const float* __restrict__ W2,
    const float* __restrict__ b1, const float* __restrict__ b2,
    ushort* __restrict__ w1bf, ushort* __restrict__ w2bf, float* __restrict__ bias,
    const int* __restrict__ dst, int* __restrict__ histG,
    int n_edges, int B_, int nb)
{
    __shared__ int h[NBMAX];
    int bid = blockIdx.x;
    if (bid < B_) {
        for (int j = threadIdx.x; j < nb; j += 256) h[j] = 0;
        __syncthreads();
        int base = bid * CHUNK;
#pragma unroll 4
        for (int i = 0; i < CHUNK / 256; ++i) {
            int e = base + i * 256 + threadIdx.x;
            if (e < n_edges) atomicAdd(&h[dst[e] >> BSH], 1);
        }
        __syncthreads();
        for (int j = threadIdx.x; j < nb; j += 256)
            histG[j * B_ + bid] = h[j];
    } else if (bid < B_ + 64) {
        int i = (bid - B_) * 256 + threadIdx.x;
        if (i < DF * DF) {
            w1bf[i] = f2bf(W1[i]);
            w2bf[i] = f2bf(W2[i]);
        }
        if (i < DF) bias[i] = b1[i] + b2[i];
    } else {
        int i = (bid - B_ - 64) * 256 + threadIdx.x;
        if (i < n4) {
            float4 v = reinterpret_cast<const float4*>(x)[i];
            ushort4 o;
            o.x = f2bf(v.x); o.y = f2bf(v.y); o.z = f2bf(v.z); o.w = f2bf(v.w);
            reinterpret_cast<ushort4*>(xbf)[i] = o;
        }
    }
}

// ---------------------------------------------------------------------------
// Hierarchical exclusive scan, phases A/B.
// final_offs(idx) = histS[idx] + bsum[idx>>10].
// ---------------------------------------------------------------------------
__global__ __launch_bounds__(256) void scan_local_kernel(
    const int* __restrict__ cnt, int* __restrict__ offs,
    int* __restrict__ bsum, int n)
{
    __shared__ int sd[256];
    int t = threadIdx.x;
    int base = blockIdx.x * 1024 + t * 4;

    int4 v = make_int4(0, 0, 0, 0);
    if (base + 3 < n) {
        v = *reinterpret_cast<const int4*>(cnt + base);
    } else {
        if (base + 0 < n) v.x = cnt[base + 0];
        if (base + 1 < n) v.y = cnt[base + 1];
        if (base + 2 < n) v.z = cnt[base + 2];
        if (base + 3 < n) v.w = cnt[base + 3];
    }
    int s = v.x + v.y + v.z + v.w;
    sd[t] = s;
    __syncthreads();
    for (int off = 1; off < 256; off <<= 1) {
        int u = (t >= off) ? sd[t - off] : 0;
        __syncthreads();
        sd[t] += u;
        __syncthreads();
    }
    int incl = sd[t];
    int excl = incl - s;
    if (t == 255) bsum[blockIdx.x] = incl;

    int p0 = excl, p1 = p0 + v.x, p2 = p1 + v.y, p3 = p2 + v.z;
    if (base + 0 < n) offs[base + 0] = p0;
    if (base + 1 < n) offs[base + 1] = p1;
    if (base + 2 < n) offs[base + 2] = p2;
    if (base + 3 < n) offs[base + 3] = p3;
}

__global__ __launch_bounds__(1024) void scan_bsum_kernel(
    int* __restrict__ bsum, int nb2)
{
    __shared__ int sd[1024];
    int t = threadIdx.x;
    int v = (t < nb2) ? bsum[t] : 0;
    sd[t] = v;
    __syncthreads();
    for (int off = 1; off < 1024; off <<= 1) {
        int u = (t >= off) ? sd[t - off] : 0;
        __syncthreads();
        sd[t] += u;
        __syncthreads();
    }
    if (t < nb2) bsum[t] = sd[t] - v;   // exclusive base per scan block
}

// ---------------------------------------------------------------------------
// Bin edges to bucket-contiguous packed array. pairs[p] = src | dstLocal<<26.
// With 64-node buckets a (bucket,block) cell avgs ~10 edges => ~42 B bursts.
// ---------------------------------------------------------------------------
__global__ __launch_bounds__(256) void bin_kernel(
    const int* __restrict__ src, const int* __restrict__ dst,
    const int* __restrict__ histS, const int* __restrict__ bsum,
    uint* __restrict__ pairs, int n_edges, int B_, int nb)
{
    __shared__ int cur[NBMAX];
    int blk = blockIdx.x;
    for (int j = threadIdx.x; j < nb; j += 256) {
        int idx = j * B_ + blk;
        cur[j] = histS[idx] + bsum[idx >> 10];
    }
    __syncthreads();
    int base = blk * CHUNK;
#pragma unroll 4
    for (int i = 0; i < CHUNK / 256; ++i) {
        int e = base + i * 256 + threadIdx.x;
        if (e < n_edges) {
            int d = dst[e];
            int j = d >> BSH;
            int p = atomicAdd(&cur[j], 1);
            pairs[p] = (uint)src[e] | ((uint)(d & (BNODES - 1)) << 26);
        }
    }
}

// ---------------------------------------------------------------------------
// Fused aggregate + MFMA GEMM. Block = 64 nodes = 1 bucket (contiguous edges).
// 512 threads = 8 waves. Gather phase: uint2 per lane, HALF-WAVE per edge
// (2 edges per load instr, 8 loads = 16 edges in flight); shfl_xor(32)
// combine. GEMM phase: 2 waves per 16-row group, 4 o-tiles each.
// ---------------------------------------------------------------------------
__global__ __launch_bounds__(512) void agg_gemm_kernel(
    const ushort* __restrict__ xbf, const uint* __restrict__ pairs,
    const int* __restrict__ histS, const int* __restrict__ bsum,
    const ushort* __restrict__ w1, const ushort* __restrict__ w2,
    const float* __restrict__ bias, float* __restrict__ out,
    int n_nodes, int n_edges, int B_, int nb, int flat)
{
    __shared__ uint sorted[TILE];           // 8 KB
    __shared__ uint abuf[64 * ASTRIDE];     // 17.4 KB
    __shared__ int hcnt[64];
    __shared__ int hoff[65];
    __shared__ int hcur[64];

    int blk  = blockIdx.x;      // == bucket index
    int node0 = blk * 64;
    int wave = threadIdx.x >> 6;
    int lane = threadIdx.x & 63;
    int halfw = lane >> 5;      // which edge of a pair
    int col  = lane & 31;       // uint2 column (8 bytes each)

    auto loadOffs = [&](int idx) -> int {
        if (idx >= flat) return n_edges;
        return histS[idx] + bsum[idx >> 10];
    };

    int e0 = loadOffs(blk * B_);
    int e1 = loadOffs((blk + 1) * B_);

    const uint2* xv2 = reinterpret_cast<const uint2*>(xbf);
    floatx4 acc4[8];
#pragma unroll
    for (int i = 0; i < 8; ++i) acc4[i] = (floatx4){0.f, 0.f, 0.f, 0.f};

    for (int t0 = e0; t0 < e1; t0 += TILE) {
        int cnt = e1 - t0; if (cnt > TILE) cnt = TILE;

        if (threadIdx.x < 64) hcnt[threadIdx.x] = 0;
        __syncthreads();

        for (int i = threadIdx.x; i < cnt; i += 512)
            atomicAdd(&hcnt[pairs[t0 + i] >> 26], 1);
        __syncthreads();

        if (threadIdx.x < 64) {
            int v = hcnt[lane];
#pragma unroll
            for (int off = 1; off < 64; off <<= 1) {
                int u = __shfl_up(v, off);
                if (lane >= off) v += u;
            }
            hoff[lane + 1] = v;
            hcur[lane] = v - hcnt[lane];
            if (lane == 0) hoff[0] = 0;
        }
        __syncthreads();

        for (int i = threadIdx.x; i < cnt; i += 512) {
            uint pk = pairs[t0 + i];
            int p = atomicAdd(&hcur[pk >> 26], 1);
            sorted[p] = pk & SRCMASK;
        }
        __syncthreads();

        // wave owns nodes wave*8 .. wave*8+7; half-wave per edge, uint2/lane
#pragma unroll
        for (int i = 0; i < 8; ++i) {
            int nl = wave * 8 + i;
            int j0 = hoff[nl], j1 = hoff[nl + 1];
            floatx4 a = acc4[i];
            int j = j0;
            for (; j + 15 < j1; j += 16) {   // 8 loads cover 16 edges
                uint2 u0 = xv2[(size_t)sorted[j +  0 + halfw] * 32 + col];
                uint2 u1 = xv2[(size_t)sorted[j +  2 + halfw] * 32 + col];
                uint2 u2 = xv2[(size_t)sorted[j +  4 + halfw] * 32 + col];
                uint2 u3 = xv2[(size_t)sorted[j +  6 + halfw] * 32 + col];
                uint2 u4 = xv2[(size_t)sorted[j +  8 + halfw] * 32 + col];
                uint2 u5 = xv2[(size_t)sorted[j + 10 + halfw] * 32 + col];
                uint2 u6 = xv2[(size_t)sorted[j + 12 + halfw] * 32 + col];
                uint2 u7 = xv2[(size_t)sorted[j + 14 + halfw] * 32 + col];
                a.x += __uint_as_float(u0.x << 16) + __uint_as_float(u1.x << 16)
                     + __uint_as_float(u2.x << 16) + __uint_as_float(u3.x << 16)
                     + __uint_as_float(u4.x << 16) + __uint_as_float(u5.x << 16)
                     + __uint_as_float(u6.x << 16) + __uint_as_float(u7.x << 16);
                a.y += __uint_as_float(u0.x & 0xffff0000u) + __uint_as_float(u1.x & 0xffff0000u)
                     + __uint_as_float(u2.x & 0xffff0000u) + __uint_as_float(u3.x & 0xffff0000u)
                     + __uint_as_float(u4.x & 0xffff0000u) + __uint_as_float(u5.x & 0xffff0000u)
                     + __uint_as_float(u6.x & 0xffff0000u) + __uint_as_float(u7.x & 0xffff0000u);
                a.z += __uint_as_float(u0.y << 16) + __uint_as_float(u1.y << 16)
                     + __uint_as_float(u2.y << 16) + __uint_as_float(u3.y << 16)
                     + __uint_as_float(u4.y << 16) + __uint_as_float(u5.y << 16)
                     + __uint_as_float(u6.y << 16) + __uint_as_float(u7.y << 16);
                a.w += __uint_as_float(u0.y & 0xffff0000u) + __uint_as_float(u1.y & 0xffff0000u)
                     + __uint_as_float(u2.y & 0xffff0000u) + __uint_as_float(u3.y & 0xffff0000u)
                     + __uint_as_float(u4.y & 0xffff0000u) + __uint_as_float(u5.y & 0xffff0000u)
                     + __uint_as_float(u6.y & 0xffff0000u) + __uint_as_float(u7.y & 0xffff0000u);
            }
            for (; j + 1 < j1; j += 2) {
                uint2 u = xv2[(size_t)sorted[j + halfw] * 32 + col];
                a.x += __uint_as_float(u.x << 16);
                a.y += __uint_as_float(u.x & 0xffff0000u);
                a.z += __uint_as_float(u.y << 16);
                a.w += __uint_as_float(u.y & 0xffff0000u);
            }
            if (j < j1 && halfw == 0) {      // odd tail: only half 0
                uint2 u = xv2[(size_t)sorted[j] * 32 + col];
                a.x += __uint_as_float(u.x << 16);
                a.y += __uint_as_float(u.x & 0xffff0000u);
                a.z += __uint_as_float(u.y << 16);
                a.w += __uint_as_float(u.y & 0xffff0000u);
            }
            acc4[i] = a;
        }
        __syncthreads();   // protect sorted/hist before next tile
    }

    // combine halves and stage aggregated rows as bf16 into LDS
#pragma unroll
    for (int i = 0; i < 8; ++i) {
        floatx4 a = acc4[i];
        a.x += __shfl_xor(a.x, 32);
        a.y += __shfl_xor(a.y, 32);
        a.z += __shfl_xor(a.z, 32);
        a.w += __shfl_xor(a.w, 32);
        if (halfw == 0) {
            int nl = wave * 8 + i;
            uint p0 = (uint)f2bf(a.x) | ((uint)f2bf(a.y) << 16);
            uint p1 = (uint)f2bf(a.z) | ((uint)f2bf(a.w) << 16);
            abuf[nl * ASTRIDE + 2 * col]     = p0;
            abuf[nl * ASTRIDE + 2 * col + 1] = p1;
        }
    }
    __syncthreads();

    // ---- MFMA phase: 2 waves per 16-row group; each does 4 of 8 o-tiles ----
    int quad = lane >> 4;
    int m    = lane & 15;
    int rg   = wave >> 1;          // row group 0..3
    int half = wave & 1;           // which 4 o-tiles
    int rowL = rg * 16 + m;
    int rowG = node0 + rowL;
    int rowC = (rowG < n_nodes) ? rowG : (n_nodes - 1);   // clamp loads

    short8 xa[4], aa[4];
#pragma unroll
    for (int ks = 0; ks < 4; ++ks) {
        xa[ks] = *reinterpret_cast<const short8*>(xbf + (size_t)rowC * DF + ks * 32 + quad * 8);
        aa[ks] = *reinterpret_cast<const short8*>(&abuf[rowL * ASTRIDE + ks * 16 + quad * 4]);
    }

    int nbase = node0 + rg * 16;
#pragma unroll
    for (int oi = 0; oi < 4; ++oi) {
        int ot = half * 4 + oi;
        int o = ot * 16 + m;
        floatx4 c = {0.f, 0.f, 0.f, 0.f};
#pragma unroll
        for (int ks = 0; ks < 4; ++ks) {
            short8 bf1 = *reinterpret_cast<const short8*>(w1 + (size_t)o * DF + ks * 32 + quad * 8);
            short8 bf2 = *reinterpret_cast<const short8*>(w2 + (size_t)o * DF + ks * 32 + quad * 8);
            c = __builtin_amdgcn_mfma_f32_16x16x32_bf16(xa[ks], bf1, c, 0, 0, 0);
            c = __builtin_amdgcn_mfma_f32_16x16x32_bf16(aa[ks], bf2, c, 0, 0, 0);
        }
        float bv = bias[o];
#pragma unroll
        for (int r = 0; r < 4; ++r) {
            int row = nbase + quad * 4 + r;
            if (row < n_nodes) out[(size_t)row * DF + o] = c[r] + bv;
        }
    }
}

extern "C" void kernel_launch(void* const* d_in, const int* in_sizes, int n_in,
                              void* d_out, int out_size, void* d_ws, size_t ws_size,
                              hipStream_t stream) {
    const float* x  = (const float*)d_in[0];
    const float* W1 = (const float*)d_in[1];
    const float* b1 = (const float*)d_in[2];
    const float* W2 = (const float*)d_in[3];
    const float* b2 = (const float*)d_in[4];
    const int* esrc = (const int*)d_in[5];
    const int* edst = (const int*)d_in[6];
    float* out = (float*)d_out;

    int n_nodes = in_sizes[0] / DF;
    int n_edges = in_sizes[5];

    int nb = (n_nodes + BNODES - 1) >> BSH;       // buckets (782)
    int B_ = (n_edges + CHUNK - 1) / CHUNK;       // edge chunks (98)
    int flat = nb * B_;                           // hist matrix size (~77k)

    char* ws = (char*)d_ws;
    ushort* xbf   = (ushort*)ws;                 ws += (size_t)n_nodes * DF * 2;
    ushort* w1bf  = (ushort*)ws;                 ws += (size_t)DF * DF * 2;
    ushort* w2bf  = (ushort*)ws;                 ws += (size_t)DF * DF * 2;
    float*  bias  = (float*)ws;                  ws += (size_t)DF * 4;
    int*    histG = (int*)ws;                    ws += (size_t)flat * 4;
    int*    histS = (int*)ws;                    ws += (size_t)(flat + 1) * 4;
    int*    bsum  = (int*)ws;                    ws += 1024 * 4;
    uint*   pairs = (uint*)ws;

    int n4 = n_nodes * DF / 4;
    int prep_blocks = B_ + 64 + (n4 + 255) / 256;
    prep_kernel<<<prep_blocks, 256, 0, stream>>>(
        x, xbf, n4, W1, W2, b1, b2, w1bf, w2bf, bias,
        edst, histG, n_edges, B_, nb);

    int nb2 = (flat + 1023) / 1024;
    scan_local_kernel<<<nb2, 256, 0, stream>>>(histG, histS, bsum, flat);
    scan_bsum_kernel<<<1, 1024, 0, stream>>>(bsum, nb2);

    bin_kernel<<<B_, 256, 0, stream>>>(esrc, edst, histS, bsum, pairs, n_edges, B_, nb);

    agg_gemm_kernel<<<nb, 512, 0, stream>>>(
        xbf, pairs, histS, bsum, w1bf, w2bf, bias, out,
        n_nodes, n_edges, B_, nb, flat);
}

// Round 10
// 179.763 us; speedup vs baseline: 1.1172x; 1.1172x over previous
//
#include <hip/hip_runtime.h>
#include <hip/hip_bf16.h>

#define DF 128
#define BSH 5                 // bucket = dst >> 5  (32 nodes / bucket)
#define BNODES 32
#define NBMAX 2048            // max buckets (50000/32 = 1563)
#define CHUNK 8192            // edges per hist/bin block
#define TILE 2048             // edges per aggregation LDS tile (bucket ~512)
#define ASTRIDE 68            // uints per abuf row (64 data + 4 pad)
#define SRCMASK 0x07ffffffu   // src in low 27 bits, dstLocal in bits 27..31

typedef __attribute__((ext_vector_type(8))) short short8;
typedef __attribute__((ext_vector_type(4))) float floatx4;

__device__ __forceinline__ ushort f2bf(float f) {
    __hip_bfloat16 h = __float2bfloat16(f);   // RNE
    return *reinterpret_cast<ushort*>(&h);
}

// ---------------------------------------------------------------------------
// Fused prep: [0,B_) hist blocks | [B_,B_+64) weight convert | rest x convert.
// ---------------------------------------------------------------------------
__global__ __launch_bounds__(256) void prep_kernel(
    const float* __restrict__ x, ushort* __restrict__ xbf, int n4,
    const float* __restrict__ W1, const float* __restrict__ W2,
    const float* __restrict__ b1, const float* __restrict__ b2,
    ushort* __restrict__ w1bf, ushort* __restrict__ w2bf, float* __restrict__ bias,
    const int* __restrict__ dst, int* __restrict__ histG,
    int n_edges, int B_, int nb)
{
    __shared__ int h[NBMAX];
    int bid = blockIdx.x;
    if (bid < B_) {
        for (int j = threadIdx.x; j < nb; j += 256) h[j] = 0;
        __syncthreads();
        int base = bid * CHUNK;
#pragma unroll 4
        for (int i = 0; i < CHUNK / 256; ++i) {
            int e = base + i * 256 + threadIdx.x;
            if (e < n_edges) atomicAdd(&h[dst[e] >> BSH], 1);
        }
        __syncthreads();
        for (int j = threadIdx.x; j < nb; j += 256)
            histG[j * B_ + bid] = h[j];
    } else if (bid < B_ + 64) {
        int i = (bid - B_) * 256 + threadIdx.x;
        if (i < DF * DF) {
            w1bf[i] = f2bf(W1[i]);
            w2bf[i] = f2bf(W2[i]);
        }
        if (i < DF) bias[i] = b1[i] + b2[i];
    } else {
        int i = (bid - B_ - 64) * 256 + threadIdx.x;
        if (i < n4) {
            float4 v = reinterpret_cast<const float4*>(x)[i];
            ushort4 o;
            o.x = f2bf(v.x); o.y = f2bf(v.y); o.z = f2bf(v.z); o.w = f2bf(v.w);
            reinterpret_cast<ushort4*>(xbf)[i] = o;
        }
    }
}

// ---------------------------------------------------------------------------
// Hierarchical exclusive scan, phases A/B.
// final_offs(idx) = histS[idx] + bsum[idx>>10].
// ---------------------------------------------------------------------------
__global__ __launch_bounds__(256) void scan_local_kernel(
    const int* __restrict__ cnt, int* __restrict__ offs,
    int* __restrict__ bsum, int n)
{
    __shared__ int sd[256];
    int t = threadIdx.x;
    int base = blockIdx.x * 1024 + t * 4;

    int4 v = make_int4(0, 0, 0, 0);
    if (base + 3 < n) {
        v = *reinterpret_cast<const int4*>(cnt + base);
    } else {
        if (base + 0 < n) v.x = cnt[base + 0];
        if (base + 1 < n) v.y = cnt[base + 1];
        if (base + 2 < n) v.z = cnt[base + 2];
        if (base + 3 < n) v.w = cnt[base + 3];
    }
    int s = v.x + v.y + v.z + v.w;
    sd[t] = s;
    __syncthreads();
    for (int off = 1; off < 256; off <<= 1) {
        int u = (t >= off) ? sd[t - off] : 0;
        __syncthreads();
        sd[t] += u;
        __syncthreads();
    }
    int incl = sd[t];
    int excl = incl - s;
    if (t == 255) bsum[blockIdx.x] = incl;

    int p0 = excl, p1 = p0 + v.x, p2 = p1 + v.y, p3 = p2 + v.z;
    if (base + 0 < n) offs[base + 0] = p0;
    if (base + 1 < n) offs[base + 1] = p1;
    if (base + 2 < n) offs[base + 2] = p2;
    if (base + 3 < n) offs[base + 3] = p3;
}

__global__ __launch_bounds__(1024) void scan_bsum_kernel(
    int* __restrict__ bsum, int nb2)
{
    __shared__ int sd[1024];
    int t = threadIdx.x;
    int v = (t < nb2) ? bsum[t] : 0;
    sd[t] = v;
    __syncthreads();
    for (int off = 1; off < 1024; off <<= 1) {
        int u = (t >= off) ? sd[t - off] : 0;
        __syncthreads();
        sd[t] += u;
        __syncthreads();
    }
    if (t < nb2) bsum[t] = sd[t] - v;   // exclusive base per scan block
}

// ---------------------------------------------------------------------------
// Bin edges to bucket-contiguous packed array. pairs[p] = src | dstLocal<<27.
// ---------------------------------------------------------------------------
__global__ __launch_bounds__(256) void bin_kernel(
    const int* __restrict__ src, const int* __restrict__ dst,
    const int* __restrict__ histS, const int* __restrict__ bsum,
    uint* __restrict__ pairs, int n_edges, int B_, int nb)
{
    __shared__ int cur[NBMAX];
    int blk = blockIdx.x;
    for (int j = threadIdx.x; j < nb; j += 256) {
        int idx = j * B_ + blk;
        cur[j] = histS[idx] + bsum[idx >> 10];
    }
    __syncthreads();
    int base = blk * CHUNK;
#pragma unroll 4
    for (int i = 0; i < CHUNK / 256; ++i) {
        int e = base + i * 256 + threadIdx.x;
        if (e < n_edges) {
            int d = dst[e];
            int j = d >> BSH;
            int p = atomicAdd(&cur[j], 1);
            pairs[p] = (uint)src[e] | ((uint)(d & (BNODES - 1)) << 27);
        }
    }
}

// ---------------------------------------------------------------------------
// Fused aggregate + MFMA GEMM. Block = 32 nodes = 1 bucket, 256 threads,
// 1563 blocks (~6 blocks/CU -> ~24 waves/CU: launch-width fixed vs R7-R9).
// Gather: wave owns 8 nodes, scalar uint per lane, 8-deep unroll.
// GEMM: 2 waves per 16-row group, 4 o-tiles each.
// ---------------------------------------------------------------------------
__global__ __launch_bounds__(256) void agg_gemm_kernel(
    const ushort* __restrict__ xbf, const uint* __restrict__ pairs,
    const int* __restrict__ histS, const int* __restrict__ bsum,
    const ushort* __restrict__ w1, const ushort* __restrict__ w2,
    const float* __restrict__ bias, float* __restrict__ out,
    int n_nodes, int n_edges, int B_, int nb, int flat)
{
    __shared__ uint sorted[TILE];               // 8 KB
    __shared__ uint abuf[BNODES * ASTRIDE];     // 8.7 KB
    __shared__ int hcnt[BNODES];
    __shared__ int hoff[BNODES + 1];
    __shared__ int hcur[BNODES];

    int blk  = blockIdx.x;      // == bucket index
    int node0 = blk * BNODES;
    int wave = threadIdx.x >> 6;
    int lane = threadIdx.x & 63;

    auto loadOffs = [&](int idx) -> int {
        if (idx >= flat) return n_edges;
        return histS[idx] + bsum[idx >> 10];
    };

    int e0 = loadOffs(blk * B_);
    int e1 = loadOffs((blk + 1) * B_);

    const uint* xv = reinterpret_cast<const uint*>(xbf);
    float2 acc[8];
#pragma unroll
    for (int i = 0; i < 8; ++i) acc[i] = make_float2(0.f, 0.f);

    for (int t0 = e0; t0 < e1; t0 += TILE) {
        int cnt = e1 - t0; if (cnt > TILE) cnt = TILE;

        if (threadIdx.x < BNODES) hcnt[threadIdx.x] = 0;
        __syncthreads();

        for (int i = threadIdx.x; i < cnt; i += 256)
            atomicAdd(&hcnt[pairs[t0 + i] >> 27], 1);
        __syncthreads();

        // 32-entry exclusive scan by wave 0 via shfl
        if (threadIdx.x < 64) {
            int v = (lane < BNODES) ? hcnt[lane] : 0;
#pragma unroll
            for (int off = 1; off < BNODES; off <<= 1) {
                int u = __shfl_up(v, off);
                if (lane >= off) v += u;
            }
            if (lane < BNODES) {
                hoff[lane + 1] = v;
                hcur[lane] = v - hcnt[lane];
            }
            if (lane == 0) hoff[0] = 0;
        }
        __syncthreads();

        for (int i = threadIdx.x; i < cnt; i += 256) {
            uint pk = pairs[t0 + i];
            int p = atomicAdd(&hcur[pk >> 27], 1);
            sorted[p] = pk & SRCMASK;
        }
        __syncthreads();

        // wave owns nodes wave*8 .. wave*8+7; 8-deep independent gathers
#pragma unroll
        for (int i = 0; i < 8; ++i) {
            int nl = wave * 8 + i;
            int j0 = hoff[nl], j1 = hoff[nl + 1];
            float2 a = acc[i];
            int j = j0;
            for (; j + 7 < j1; j += 8) {
                uint u0 = xv[(size_t)sorted[j + 0] * 64 + lane];
                uint u1 = xv[(size_t)sorted[j + 1] * 64 + lane];
                uint u2 = xv[(size_t)sorted[j + 2] * 64 + lane];
                uint u3 = xv[(size_t)sorted[j + 3] * 64 + lane];
                uint u4 = xv[(size_t)sorted[j + 4] * 64 + lane];
                uint u5 = xv[(size_t)sorted[j + 5] * 64 + lane];
                uint u6 = xv[(size_t)sorted[j + 6] * 64 + lane];
                uint u7 = xv[(size_t)sorted[j + 7] * 64 + lane];
                a.x += __uint_as_float(u0 << 16) + __uint_as_float(u1 << 16)
                     + __uint_as_float(u2 << 16) + __uint_as_float(u3 << 16)
                     + __uint_as_float(u4 << 16) + __uint_as_float(u5 << 16)
                     + __uint_as_float(u6 << 16) + __uint_as_float(u7 << 16);
                a.y += __uint_as_float(u0 & 0xffff0000u) + __uint_as_float(u1 & 0xffff0000u)
                     + __uint_as_float(u2 & 0xffff0000u) + __uint_as_float(u3 & 0xffff0000u)
                     + __uint_as_float(u4 & 0xffff0000u) + __uint_as_float(u5 & 0xffff0000u)
                     + __uint_as_float(u6 & 0xffff0000u) + __uint_as_float(u7 & 0xffff0000u);
            }
            for (; j + 3 < j1; j += 4) {
                uint u0 = xv[(size_t)sorted[j + 0] * 64 + lane];
                uint u1 = xv[(size_t)sorted[j + 1] * 64 + lane];
                uint u2 = xv[(size_t)sorted[j + 2] * 64 + lane];
                uint u3 = xv[(size_t)sorted[j + 3] * 64 + lane];
                a.x += __uint_as_float(u0 << 16) + __uint_as_float(u1 << 16)
                     + __uint_as_float(u2 << 16) + __uint_as_float(u3 << 16);
                a.y += __uint_as_float(u0 & 0xffff0000u) + __uint_as_float(u1 & 0xffff0000u)
                     + __uint_as_float(u2 & 0xffff0000u) + __uint_as_float(u3 & 0xffff0000u);
            }
            for (; j < j1; ++j) {
                uint u = xv[(size_t)sorted[j] * 64 + lane];
                a.x += __uint_as_float(u << 16);
                a.y += __uint_as_float(u & 0xffff0000u);
            }
            acc[i] = a;
        }
        __syncthreads();   // protect sorted/hist before next tile
    }

    // stage aggregated rows as bf16 into LDS (row stride 68 uints)
#pragma unroll
    for (int i = 0; i < 8; ++i) {
        int nl = wave * 8 + i;
        abuf[nl * ASTRIDE + lane] =
            (uint)f2bf(acc[i].x) | ((uint)f2bf(acc[i].y) << 16);
    }
    __syncthreads();

    // ---- MFMA phase: 2 waves per 16-row group; each does 4 of 8 o-tiles ----
    int quad = lane >> 4;
    int m    = lane & 15;
    int rg   = wave >> 1;          // row group 0..1
    int half = wave & 1;           // which 4 o-tiles
    int rowL = rg * 16 + m;
    int rowG = node0 + rowL;
    int rowC = (rowG < n_nodes) ? rowG : (n_nodes - 1);   // clamp loads

    short8 xa[4], aa[4];
#pragma unroll
    for (int ks = 0; ks < 4; ++ks) {
        xa[ks] = *reinterpret_cast<const short8*>(xbf + (size_t)rowC * DF + ks * 32 + quad * 8);
        aa[ks] = *reinterpret_cast<const short8*>(&abuf[rowL * ASTRIDE + ks * 16 + quad * 4]);
    }

    int nbase = node0 + rg * 16;
#pragma unroll
    for (int oi = 0; oi < 4; ++oi) {
        int ot = half * 4 + oi;
        int o = ot * 16 + m;
        floatx4 c = {0.f, 0.f, 0.f, 0.f};
#pragma unroll
        for (int ks = 0; ks < 4; ++ks) {
            short8 bf1 = *reinterpret_cast<const short8*>(w1 + (size_t)o * DF + ks * 32 + quad * 8);
            short8 bf2 = *reinterpret_cast<const short8*>(w2 + (size_t)o * DF + ks * 32 + quad * 8);
            c = __builtin_amdgcn_mfma_f32_16x16x32_bf16(xa[ks], bf1, c, 0, 0, 0);
            c = __builtin_amdgcn_mfma_f32_16x16x32_bf16(aa[ks], bf2, c, 0, 0, 0);
        }
        float bv = bias[o];
#pragma unroll
        for (int r = 0; r < 4; ++r) {
            int row = nbase + quad * 4 + r;
            if (row < n_nodes) out[(size_t)row * DF + o] = c[r] + bv;
        }
    }
}

extern "C" void kernel_launch(void* const* d_in, const int* in_sizes, int n_in,
                              void* d_out, int out_size, void* d_ws, size_t ws_size,
                              hipStream_t stream) {
    const float* x  = (const float*)d_in[0];
    const float* W1 = (const float*)d_in[1];
    const float* b1 = (const float*)d_in[2];
    const float* W2 = (const float*)d_in[3];
    const float* b2 = (const float*)d_in[4];
    const int* esrc = (const int*)d_in[5];
    const int* edst = (const int*)d_in[6];
    float* out = (float*)d_out;

    int n_nodes = in_sizes[0] / DF;
    int n_edges = in_sizes[5];

    int nb = (n_nodes + BNODES - 1) >> BSH;       // buckets (1563)
    int B_ = (n_edges + CHUNK - 1) / CHUNK;       // edge chunks (98)
    int flat = nb * B_;                           // hist matrix size (~153k)

    char* ws = (char*)d_ws;
    ushort* xbf   = (ushort*)ws;                 ws += (size_t)n_nodes * DF * 2;
    ushort* w1bf  = (ushort*)ws;                 ws += (size_t)DF * DF * 2;
    ushort* w2bf  = (ushort*)ws;                 ws += (size_t)DF * DF * 2;
    float*  bias  = (float*)ws;                  ws += (size_t)DF * 4;
    int*    histG = (int*)ws;                    ws += (size_t)flat * 4;
    int*    histS = (int*)ws;                    ws += (size_t)(flat + 1) * 4;
    int*    bsum  = (int*)ws;                    ws += 1024 * 4;
    uint*   pairs = (uint*)ws;

    int n4 = n_nodes * DF / 4;
    int prep_blocks = B_ + 64 + (n4 + 255) / 256;
    prep_kernel<<<prep_blocks, 256, 0, stream>>>(
        x, xbf, n4, W1, W2, b1, b2, w1bf, w2bf, bias,
        edst, histG, n_edges, B_, nb);

    int nb2 = (flat + 1023) / 1024;
    scan_local_kernel<<<nb2, 256, 0, stream>>>(histG, histS, bsum, flat);
    scan_bsum_kernel<<<1, 1024, 0, stream>>>(bsum, nb2);

    bin_kernel<<<B_, 256, 0, stream>>>(esrc, edst, histS, bsum, pairs, n_edges, B_, nb);

    agg_gemm_kernel<<<nb, 256, 0, stream>>>(
        xbf, pairs, histS, bsum, w1bf, w2bf, bias, out,
        n_nodes, n_edges, B_, nb, flat);
}

// Round 11
// 178.359 us; speedup vs baseline: 1.1260x; 1.0079x over previous
//
#include <hip/hip_runtime.h>
#include <hip/hip_bf16.h>

#define DF 128
#define BSH 5                 // bucket = dst >> 5  (32 nodes / bucket)
#define BNODES 32
#define NBMAX 2048            // max buckets (50000/32 = 1563)
#define CHUNK 8192            // edges per hist/bin block
#define BMAX 128              // max edge chunks (98 here; scan assumes <=128)
#define TILE 2048             // edges per aggregation LDS tile (bucket ~512)
#define ASTRIDE 68            // uints per abuf row (64 data + 4 pad)
#define SRCMASK 0x07ffffffu   // src in low 27 bits, dstLocal in bits 27..31

typedef __attribute__((ext_vector_type(8))) short short8;
typedef __attribute__((ext_vector_type(4))) float floatx4;

__device__ __forceinline__ ushort f2bf(float f) {
    __hip_bfloat16 h = __float2bfloat16(f);   // RNE
    return *reinterpret_cast<ushort*>(&h);
}

// ---------------------------------------------------------------------------
// Fused prep: [0,B_) hist blocks | [B_,B_+64) weight convert | rest x convert.
// histG layout: [block][bucket] (block-major -> flat scan assigns each bin
// block a contiguous output region).
// ---------------------------------------------------------------------------
__global__ __launch_bounds__(256) void prep_kernel(
    const float* __restrict__ x, ushort* __restrict__ xbf, int n4,
    const float* __restrict__ W1, const float* __restrict__ W2,
    const float* __restrict__ b1, const float* __restrict__ b2,
    ushort* __restrict__ w1bf, ushort* __restrict__ w2bf, float* __restrict__ bias,
    const int* __restrict__ dst, int* __restrict__ histG,
    int n_edges, int B_, int nb)
{
    __shared__ int h[NBMAX];
    int bid = blockIdx.x;
    if (bid < B_) {
        for (int j = threadIdx.x; j < nb; j += 256) h[j] = 0;
        __syncthreads();
        int base = bid * CHUNK;
#pragma unroll 4
        for (int i = 0; i < CHUNK / 256; ++i) {
            int e = base + i * 256 + threadIdx.x;
            if (e < n_edges) atomicAdd(&h[dst[e] >> BSH], 1);
        }
        __syncthreads();
        for (int j = threadIdx.x; j < nb; j += 256)
            histG[bid * nb + j] = h[j];
    } else if (bid < B_ + 64) {
        int i = (bid - B_) * 256 + threadIdx.x;
        if (i < DF * DF) {
            w1bf[i] = f2bf(W1[i]);
            w2bf[i] = f2bf(W2[i]);
        }
        if (i < DF) bias[i] = b1[i] + b2[i];
    } else {
        int i = (bid - B_ - 64) * 256 + threadIdx.x;
        if (i < n4) {
            float4 v = reinterpret_cast<const float4*>(x)[i];
            ushort4 o;
            o.x = f2bf(v.x); o.y = f2bf(v.y); o.z = f2bf(v.z); o.w = f2bf(v.w);
            reinterpret_cast<ushort4*>(xbf)[i] = o;
        }
    }
}

// ---------------------------------------------------------------------------
// Hierarchical exclusive scan, phases A/B.
// final_offs(idx) = histS[idx] + bsum[idx>>10].
// ---------------------------------------------------------------------------
__global__ __launch_bounds__(256) void scan_local_kernel(
    const int* __restrict__ cnt, int* __restrict__ offs,
    int* __restrict__ bsum, int n)
{
    __shared__ int sd[256];
    int t = threadIdx.x;
    int base = blockIdx.x * 1024 + t * 4;

    int4 v = make_int4(0, 0, 0, 0);
    if (base + 3 < n) {
        v = *reinterpret_cast<const int4*>(cnt + base);
    } else {
        if (base + 0 < n) v.x = cnt[base + 0];
        if (base + 1 < n) v.y = cnt[base + 1];
        if (base + 2 < n) v.z = cnt[base + 2];
        if (base + 3 < n) v.w = cnt[base + 3];
    }
    int s = v.x + v.y + v.z + v.w;
    sd[t] = s;
    __syncthreads();
    for (int off = 1; off < 256; off <<= 1) {
        int u = (t >= off) ? sd[t - off] : 0;
        __syncthreads();
        sd[t] += u;
        __syncthreads();
    }
    int incl = sd[t];
    int excl = incl - s;
    if (t == 255) bsum[blockIdx.x] = incl;

    int p0 = excl, p1 = p0 + v.x, p2 = p1 + v.y, p3 = p2 + v.z;
    if (base + 0 < n) offs[base + 0] = p0;
    if (base + 1 < n) offs[base + 1] = p1;
    if (base + 2 < n) offs[base + 2] = p2;
    if (base + 3 < n) offs[base + 3] = p3;
}

__global__ __launch_bounds__(1024) void scan_bsum_kernel(
    int* __restrict__ bsum, int nb2)
{
    __shared__ int sd[1024];
    int t = threadIdx.x;
    int v = (t < nb2) ? bsum[t] : 0;
    sd[t] = v;
    __syncthreads();
    for (int off = 1; off < 1024; off <<= 1) {
        int u = (t >= off) ? sd[t - off] : 0;
        __syncthreads();
        sd[t] += u;
        __syncthreads();
    }
    if (t < nb2) bsum[t] = sd[t] - v;   // exclusive base per scan block
}

// ---------------------------------------------------------------------------
// Bin: sort this block's CHUNK edges by bucket into LDS, then write its OWN
// CONTIGUOUS region [blk*CHUNK, blk*CHUNK+cnt) with coalesced stores.
// pairs[p] = src | dstLocal<<27.
// ---------------------------------------------------------------------------
__global__ __launch_bounds__(1024) void bin_kernel(
    const int* __restrict__ src, const int* __restrict__ dst,
    const int* __restrict__ histS, const int* __restrict__ bsum,
    uint* __restrict__ pairs, int n_edges, int B_, int nb)
{
    __shared__ int  cur[NBMAX];     // 8 KB global cursors
    __shared__ uint stage[CHUNK];   // 32 KB
    int blk = blockIdx.x;
    for (int j = threadIdx.x; j < nb; j += 1024) {
        int idx = blk * nb + j;
        cur[j] = histS[idx] + bsum[idx >> 10];
    }
    __syncthreads();
    int base = blk * CHUNK;
    int cnt = n_edges - base; if (cnt > CHUNK) cnt = CHUNK;
    for (int i = threadIdx.x; i < cnt; i += 1024) {
        int e = base + i;
        int d = dst[e];
        int j = d >> BSH;
        int p = atomicAdd(&cur[j], 1);
        stage[p - base] = (uint)src[e] | ((uint)(d & (BNODES - 1)) << 27);
    }
    __syncthreads();
    for (int i = threadIdx.x; i < cnt; i += 1024)
        pairs[base + i] = stage[i];
}

// ---------------------------------------------------------------------------
// Fused aggregate + MFMA GEMM. Block = 32 nodes = 1 bucket, 256 threads,
// 1563 blocks. Bucket's edges live in <=B_ runs (one per bin block);
// runs are located via the scanned histogram, staged through LDS with a
// 7-step binary search, node-sorted, then register-gathered. MFMA epilogue.
// ---------------------------------------------------------------------------
__global__ __launch_bounds__(256) void agg_gemm_kernel(
    const ushort* __restrict__ xbf, const uint* __restrict__ pairs,
    const int* __restrict__ histS, const int* __restrict__ bsum,
    const ushort* __restrict__ w1, const ushort* __restrict__ w2,
    const float* __restrict__ bias, float* __restrict__ out,
    int n_nodes, int n_edges, int B_, int nb, int flat)
{
    __shared__ uint raw[TILE];                  // 8 KB
    __shared__ uint sorted[TILE];               // 8 KB
    __shared__ uint abuf[BNODES * ASTRIDE];     // 8.7 KB
    __shared__ int  rstart[BMAX];
    __shared__ int  rexcl[BMAX + 1];
    __shared__ int hcnt[BNODES];
    __shared__ int hoff[BNODES + 1];
    __shared__ int hcur[BNODES];

    int blk  = blockIdx.x;      // == bucket index
    int node0 = blk * BNODES;
    int wave = threadIdx.x >> 6;
    int lane = threadIdx.x & 63;

    auto loadOffs = [&](int idx) -> int {
        if (idx >= flat) return n_edges;
        return histS[idx] + bsum[idx >> 10];
    };

    // runs: block j's cell for this bucket = [offs(j*nb+blk), offs(j*nb+blk+1))
    if (threadIdx.x < B_) {
        int idx = threadIdx.x * nb + blk;
        int s = loadOffs(idx);
        rstart[threadIdx.x] = s;
        rexcl[threadIdx.x]  = loadOffs(idx + 1) - s;   // count (temp)
    }
    __syncthreads();
    if (threadIdx.x < 64) {                            // wave 0: scan <=128 counts
        int c0 = (lane < B_) ? rexcl[lane] : 0;
        int c1 = (64 + lane < B_) ? rexcl[64 + lane] : 0;
        int s0 = c0, s1 = c1;
#pragma unroll
        for (int off = 1; off < 64; off <<= 1) {
            int u0 = __shfl_up(s0, off);
            int u1 = __shfl_up(s1, off);
            if (lane >= off) { s0 += u0; s1 += u1; }
        }
        int t0 = __shfl(s0, 63);
        int t1 = __shfl(s1, 63);
        if (lane < B_) rexcl[lane] = s0 - c0;
        if (64 + lane < B_) rexcl[64 + lane] = t0 + s1 - c1;
        if (lane == 0) rexcl[B_] = t0 + t1;            // total
    }
    __syncthreads();
    int total = rexcl[B_];

    const uint* xv = reinterpret_cast<const uint*>(xbf);
    float2 acc[8];
#pragma unroll
    for (int i = 0; i < 8; ++i) acc[i] = make_float2(0.f, 0.f);

    for (int t0 = 0; t0 < total; t0 += TILE) {
        int cnt = total - t0; if (cnt > TILE) cnt = TILE;

        if (threadIdx.x < BNODES) hcnt[threadIdx.x] = 0;
        __syncthreads();

        // stage tile: binary-search the run, read pairs, node-histogram
        for (int i = threadIdx.x; i < cnt; i += 256) {
            int t = t0 + i;
            int lo = 0, hi = B_;
            while (lo + 1 < hi) {
                int mid = (lo + hi) >> 1;
                if (rexcl[mid] <= t) lo = mid; else hi = mid;
            }
            uint pk = pairs[rstart[lo] + (t - rexcl[lo])];
            raw[i] = pk;
            atomicAdd(&hcnt[pk >> 27], 1);
        }
        __syncthreads();

        // 32-entry exclusive scan by wave 0 via shfl
        if (threadIdx.x < 64) {
            int v = (lane < BNODES) ? hcnt[lane] : 0;
#pragma unroll
            for (int off = 1; off < BNODES; off <<= 1) {
                int u = __shfl_up(v, off);
                if (lane >= off) v += u;
            }
            if (lane < BNODES) {
                hoff[lane + 1] = v;
                hcur[lane] = v - hcnt[lane];
            }
            if (lane == 0) hoff[0] = 0;
        }
        __syncthreads();

        for (int i = threadIdx.x; i < cnt; i += 256) {
            uint pk = raw[i];
            int p = atomicAdd(&hcur[pk >> 27], 1);
            sorted[p] = pk & SRCMASK;
        }
        __syncthreads();

        // wave owns nodes wave*8 .. wave*8+7; 8-deep independent gathers
#pragma unroll
        for (int i = 0; i < 8; ++i) {
            int nl = wave * 8 + i;
            int j0 = hoff[nl], j1 = hoff[nl + 1];
            float2 a = acc[i];
            int j = j0;
            for (; j + 7 < j1; j += 8) {
                uint u0 = xv[(size_t)sorted[j + 0] * 64 + lane];
                uint u1 = xv[(size_t)sorted[j + 1] * 64 + lane];
                uint u2 = xv[(size_t)sorted[j + 2] * 64 + lane];
                uint u3 = xv[(size_t)sorted[j + 3] * 64 + lane];
                uint u4 = xv[(size_t)sorted[j + 4] * 64 + lane];
                uint u5 = xv[(size_t)sorted[j + 5] * 64 + lane];
                uint u6 = xv[(size_t)sorted[j + 6] * 64 + lane];
                uint u7 = xv[(size_t)sorted[j + 7] * 64 + lane];
                a.x += __uint_as_float(u0 << 16) + __uint_as_float(u1 << 16)
                     + __uint_as_float(u2 << 16) + __uint_as_float(u3 << 16)
                     + __uint_as_float(u4 << 16) + __uint_as_float(u5 << 16)
                     + __uint_as_float(u6 << 16) + __uint_as_float(u7 << 16);
                a.y += __uint_as_float(u0 & 0xffff0000u) + __uint_as_float(u1 & 0xffff0000u)
                     + __uint_as_float(u2 & 0xffff0000u) + __uint_as_float(u3 & 0xffff0000u)
                     + __uint_as_float(u4 & 0xffff0000u) + __uint_as_float(u5 & 0xffff0000u)
                     + __uint_as_float(u6 & 0xffff0000u) + __uint_as_float(u7 & 0xffff0000u);
            }
            for (; j + 3 < j1; j += 4) {
                uint u0 = xv[(size_t)sorted[j + 0] * 64 + lane];
                uint u1 = xv[(size_t)sorted[j + 1] * 64 + lane];
                uint u2 = xv[(size_t)sorted[j + 2] * 64 + lane];
                uint u3 = xv[(size_t)sorted[j + 3] * 64 + lane];
                a.x += __uint_as_float(u0 << 16) + __uint_as_float(u1 << 16)
                     + __uint_as_float(u2 << 16) + __uint_as_float(u3 << 16);
                a.y += __uint_as_float(u0 & 0xffff0000u) + __uint_as_float(u1 & 0xffff0000u)
                     + __uint_as_float(u2 & 0xffff0000u) + __uint_as_float(u3 & 0xffff0000u);
            }
            for (; j < j1; ++j) {
                uint u = xv[(size_t)sorted[j] * 64 + lane];
                a.x += __uint_as_float(u << 16);
                a.y += __uint_as_float(u & 0xffff0000u);
            }
            acc[i] = a;
        }
        __syncthreads();   // protect raw/sorted/hist before next tile
    }

    // stage aggregated rows as bf16 into LDS (row stride 68 uints)
#pragma unroll
    for (int i = 0; i < 8; ++i) {
        int nl = wave * 8 + i;
        abuf[nl * ASTRIDE + lane] =
            (uint)f2bf(acc[i].x) | ((uint)f2bf(acc[i].y) << 16);
    }
    __syncthreads();

    // ---- MFMA phase: 2 waves per 16-row group; each does 4 of 8 o-tiles ----
    int quad = lane >> 4;
    int m    = lane & 15;
    int rg   = wave >> 1;          // row group 0..1
    int half = wave & 1;           // which 4 o-tiles
    int rowL = rg * 16 + m;
    int rowG = node0 + rowL;
    int rowC = (rowG < n_nodes) ? rowG : (n_nodes - 1);   // clamp loads

    short8 xa[4], aa[4];
#pragma unroll
    for (int ks = 0; ks < 4; ++ks) {
        xa[ks] = *reinterpret_cast<const short8*>(xbf + (size_t)rowC * DF + ks * 32 + quad * 8);
        aa[ks] = *reinterpret_cast<const short8*>(&abuf[rowL * ASTRIDE + ks * 16 + quad * 4]);
    }

    int nbase = node0 + rg * 16;
#pragma unroll
    for (int oi = 0; oi < 4; ++oi) {
        int ot = half * 4 + oi;
        int o = ot * 16 + m;
        floatx4 c = {0.f, 0.f, 0.f, 0.f};
#pragma unroll
        for (int ks = 0; ks < 4; ++ks) {
            short8 bf1 = *reinterpret_cast<const short8*>(w1 + (size_t)o * DF + ks * 32 + quad * 8);
            short8 bf2 = *reinterpret_cast<const short8*>(w2 + (size_t)o * DF + ks * 32 + quad * 8);
            c = __builtin_amdgcn_mfma_f32_16x16x32_bf16(xa[ks], bf1, c, 0, 0, 0);
            c = __builtin_amdgcn_mfma_f32_16x16x32_bf16(aa[ks], bf2, c, 0, 0, 0);
        }
        float bv = bias[o];
#pragma unroll
        for (int r = 0; r < 4; ++r) {
            int row = nbase + quad * 4 + r;
            if (row < n_nodes) out[(size_t)row * DF + o] = c[r] + bv;
        }
    }
}

extern "C" void kernel_launch(void* const* d_in, const int* in_sizes, int n_in,
                              void* d_out, int out_size, void* d_ws, size_t ws_size,
                              hipStream_t stream) {
    const float* x  = (const float*)d_in[0];
    const float* W1 = (const float*)d_in[1];
    const float* b1 = (const float*)d_in[2];
    const float* W2 = (const float*)d_in[3];
    const float* b2 = (const float*)d_in[4];
    const int* esrc = (const int*)d_in[5];
    const int* edst = (const int*)d_in[6];
    float* out = (float*)d_out;

    int n_nodes = in_sizes[0] / DF;
    int n_edges = in_sizes[5];

    int nb = (n_nodes + BNODES - 1) >> BSH;       // buckets (1563)
    int B_ = (n_edges + CHUNK - 1) / CHUNK;       // edge chunks (98, <= BMAX)
    int flat = nb * B_;                           // hist matrix size (~153k)

    char* ws = (char*)d_ws;
    ushort* xbf   = (ushort*)ws;                 ws += (size_t)n_nodes * DF * 2;
    ushort* w1bf  = (ushort*)ws;                 ws += (size_t)DF * DF * 2;
    ushort* w2bf  = (ushort*)ws;                 ws += (size_t)DF * DF * 2;
    float*  bias  = (float*)ws;                  ws += (size_t)DF * 4;
    int*    histG = (int*)ws;                    ws += (size_t)flat * 4;
    int*    histS = (int*)ws;                    ws += (size_t)(flat + 1) * 4;
    int*    bsum  = (int*)ws;                    ws += 1024 * 4;
    uint*   pairs = (uint*)ws;

    int n4 = n_nodes * DF / 4;
    int prep_blocks = B_ + 64 + (n4 + 255) / 256;
    prep_kernel<<<prep_blocks, 256, 0, stream>>>(
        x, xbf, n4, W1, W2, b1, b2, w1bf, w2bf, bias,
        edst, histG, n_edges, B_, nb);

    int nb2 = (flat + 1023) / 1024;
    scan_local_kernel<<<nb2, 256, 0, stream>>>(histG, histS, bsum, flat);
    scan_bsum_kernel<<<1, 1024, 0, stream>>>(bsum, nb2);

    bin_kernel<<<B_, 1024, 0, stream>>>(esrc, edst, histS, bsum, pairs, n_edges, B_, nb);

    agg_gemm_kernel<<<nb, 256, 0, stream>>>(
        xbf, pairs, histS, bsum, w1bf, w2bf, bias, out,
        n_nodes, n_edges, B_, nb, flat);
}